// Round 5
// baseline (1705.133 us; speedup 1.0000x reference)
//
#include <hip/hip_runtime.h>

// ---------------------------------------------------------------------------
// Recurrent GraphSAGE net. Round 5: fused aggregate+GEMM conv kernels.
//  - conv_fused: 64 nodes/block. Phase 1: 256 threads mean-aggregate neighbor
//    rows (bf16 gather, fp32 accum) into padded LDS tile (64 x 136 ushort,
//    row stride 272B -> conflict-free ds_read_b128). Phase 2: 4 waves x 16
//    nodes MFMA: out = relu([agg|x] @ [Wl;Wr]^T + b). No aggb roundtrip.
//  - conv_head_fused: same + head (x_new = xprev + relu(h)@linW^T + linb)
//    reduced in-register, writes out[:,t,:] and xprev.
//  - gather is at a ~10 TB/s random-access plateau (R4 evidence: unroll 4->8
//    neutral); GEMM rides inside its shadow via 4 blocks/CU co-residency.
// Per timestep: enc1, conv(e2), conv(d1), conv+head(d2) = 4 dispatches.
// ---------------------------------------------------------------------------

typedef __attribute__((ext_vector_type(8))) short short8;
typedef __attribute__((ext_vector_type(8))) unsigned short ushort8;
typedef __attribute__((ext_vector_type(4))) float f32x4;

static __device__ __forceinline__ float b2f(unsigned short u) {
  return __uint_as_float(((unsigned int)u) << 16);
}
static __device__ __forceinline__ unsigned short f2bf(float f) {
  unsigned int u = __float_as_uint(f);
  u += 0x7FFFu + ((u >> 16) & 1u);   // round-nearest-even
  return (unsigned short)(u >> 16);
}

// ---------------- graph preprocessing ----------------

__global__ void count_rank_kernel(const int* __restrict__ dst, int* __restrict__ cnt,
                                  int* __restrict__ rank, int E) {
  int e = blockIdx.x * blockDim.x + threadIdx.x;
  if (e < E) rank[e] = atomicAdd(&cnt[dst[e]], 1);
}

__global__ __launch_bounds__(256) void blocksum_kernel(const int* __restrict__ cnt,
                                                       int* __restrict__ bsum, int n) {
  __shared__ int s[256];
  int tid = threadIdx.x;
  int i = blockIdx.x * 256 + tid;
  s[tid] = (i < n) ? cnt[i] : 0;
  __syncthreads();
  for (int off = 128; off > 0; off >>= 1) {
    if (tid < off) s[tid] += s[tid + off];
    __syncthreads();
  }
  if (tid == 0) bsum[blockIdx.x] = s[0];
}

__global__ __launch_bounds__(256) void scan_sums_kernel(const int* __restrict__ bsum,
                                                        int* __restrict__ boff, int nb) {
  __shared__ int s[256];
  int tid = threadIdx.x;
  int v = (tid < nb) ? bsum[tid] : 0;
  s[tid] = v;
  __syncthreads();
  for (int off = 1; off < 256; off <<= 1) {
    int t = (tid >= off) ? s[tid - off] : 0;
    __syncthreads();
    s[tid] += t;
    __syncthreads();
  }
  if (tid < nb) boff[tid] = s[tid] - v;   // exclusive
}

__global__ __launch_bounds__(256) void expand_kernel(const int* __restrict__ cnt,
                                                     const int* __restrict__ boff,
                                                     int* __restrict__ row_ptr,
                                                     float* __restrict__ rdeg, int n) {
  __shared__ int s[256];
  int tid = threadIdx.x;
  int i = blockIdx.x * 256 + tid;
  int v = (i < n) ? cnt[i] : 0;
  s[tid] = v;
  __syncthreads();
  for (int off = 1; off < 256; off <<= 1) {
    int t = (tid >= off) ? s[tid - off] : 0;
    __syncthreads();
    s[tid] += t;
    __syncthreads();
  }
  if (i < n) {
    row_ptr[i + 1] = boff[blockIdx.x] + s[tid];
    rdeg[i] = 1.0f / fmaxf((float)v, 1.0f);
  }
  if (i == 0) row_ptr[0] = 0;
}

// no atomics: slot position = row_ptr[dst] + rank (recorded during count)
__global__ void fill_csr2_kernel(const int* __restrict__ src, const int* __restrict__ dst,
                                 const int* __restrict__ rank, const int* __restrict__ row_ptr,
                                 int* __restrict__ col, int E) {
  int e = blockIdx.x * blockDim.x + threadIdx.x;
  if (e < E) col[row_ptr[dst[e]] + rank[e]] = src[e];
}

// convert all 6 conv weight matrices (128x128 each) in one dispatch
__global__ void f2bf6_kernel(const float* __restrict__ s0, const float* __restrict__ s1,
                             const float* __restrict__ s2, const float* __restrict__ s3,
                             const float* __restrict__ s4, const float* __restrict__ s5,
                             unsigned short* __restrict__ dst) {
  int i = blockIdx.x * blockDim.x + threadIdx.x;
  if (i >= 6 * 16384) return;
  int m = i >> 14, o = i & 16383;
  const float* s;
  switch (m) {
    case 0: s = s0; break; case 1: s = s1; break; case 2: s = s2; break;
    case 3: s = s3; break; case 4: s = s4; break; default: s = s5; break;
  }
  dst[i] = f2bf(s[o]);
}

// mean-aggregate mesh (8 fp32 ch): 2 lanes/node, float4/lane, once per launch
__global__ void aggmesh_kernel(const float* __restrict__ mesh, float* __restrict__ aggm,
                               const int* __restrict__ row_ptr, const int* __restrict__ col,
                               const float* __restrict__ rdeg, int N) {
  int g = blockIdx.x * blockDim.x + threadIdx.x;
  int node = g >> 1, h = (g & 1) * 4;
  if (node >= N) return;
  int j0 = row_ptr[node], j1 = row_ptr[node + 1];
  float4 acc = make_float4(0.f, 0.f, 0.f, 0.f);
  int j = j0;
  for (; j + 4 <= j1; j += 4) {
    float4 v0 = *(const float4*)&mesh[col[j] * 8 + h];
    float4 v1 = *(const float4*)&mesh[col[j + 1] * 8 + h];
    float4 v2 = *(const float4*)&mesh[col[j + 2] * 8 + h];
    float4 v3 = *(const float4*)&mesh[col[j + 3] * 8 + h];
    acc.x += (v0.x + v1.x) + (v2.x + v3.x);
    acc.y += (v0.y + v1.y) + (v2.y + v3.y);
    acc.z += (v0.z + v1.z) + (v2.z + v3.z);
    acc.w += (v0.w + v1.w) + (v2.w + v3.w);
  }
  for (; j < j1; ++j) {
    float4 v0 = *(const float4*)&mesh[col[j] * 8 + h];
    acc.x += v0.x; acc.y += v0.y; acc.z += v0.z; acc.w += v0.w;
  }
  float r = rdeg[node];
  acc.x *= r; acc.y *= r; acc.z *= r; acc.w *= r;
  *(float4*)&aggm[node * 8 + h] = acc;
}

// mterm[n][o] = bl[o] + sum_k Wl[o][4+k]*aggm[n][k] + Wr[o][4+k]*mesh[n][k]
__global__ void mesh_term_kernel(const float* __restrict__ aggm, const float* __restrict__ mesh,
                                 const float* __restrict__ Wl, const float* __restrict__ Wr,
                                 const float* __restrict__ bl, unsigned short* __restrict__ mterm,
                                 int N) {
  int g = blockIdx.x * blockDim.x + threadIdx.x;
  if (g >= N * 128) return;
  int n = g >> 7, o = g & 127;
  float acc = bl[o];
#pragma unroll
  for (int k = 0; k < 8; ++k)
    acc += Wl[o * 12 + 4 + k] * aggm[n * 8 + k] + Wr[o * 12 + 4 + k] * mesh[n * 8 + k];
  mterm[g] = f2bf(acc);
}

// ---------------- per-timestep kernels ----------------

// enc1: gather xprev (float4 rows), K=8 GEMM, + mterm, relu -> bf16.
__global__ __launch_bounds__(256) void enc1_kernel(
    const float* __restrict__ xprev, const int* __restrict__ row_ptr,
    const int* __restrict__ col, const float* __restrict__ rdeg,
    const float* __restrict__ Wl, const float* __restrict__ Wr,
    const unsigned short* __restrict__ mterm, unsigned short* __restrict__ out, int N) {
  __shared__ float Wx[8][128];   // k<4: Wl[:, k]; k>=4: Wr[:, k-4]
  __shared__ float4 part[256];
  __shared__ float As[64][8];    // [node][aggx(4) | own(4)]
  int tid = threadIdx.x;
  int nb = blockIdx.x * 64;
  for (int i = tid; i < 1024; i += 256) {
    int k = i >> 7, o = i & 127;
    Wx[k][o] = (k < 4) ? Wl[o * 12 + k] : Wr[o * 12 + (k - 4)];
  }
  int nl = tid >> 2, q = tid & 3;
  int gn = nb + nl; if (gn > N - 1) gn = N - 1;
  int j0 = row_ptr[gn], j1 = row_ptr[gn + 1];
  int per = (j1 - j0 + 3) >> 2;
  int a = j0 + q * per; if (a > j1) a = j1;
  int b = a + per; if (b > j1) b = j1;
  float4 acc = make_float4(0.f, 0.f, 0.f, 0.f);
  int j = a;
  for (; j + 2 <= b; j += 2) {
    float4 v0 = *(const float4*)&xprev[col[j] * 4];
    float4 v1 = *(const float4*)&xprev[col[j + 1] * 4];
    acc.x += v0.x + v1.x; acc.y += v0.y + v1.y;
    acc.z += v0.z + v1.z; acc.w += v0.w + v1.w;
  }
  if (j < b) {
    float4 v0 = *(const float4*)&xprev[col[j] * 4];
    acc.x += v0.x; acc.y += v0.y; acc.z += v0.z; acc.w += v0.w;
  }
  part[tid] = acc;
  __syncthreads();
  if (tid < 64) {
    int g2 = nb + tid; if (g2 > N - 1) g2 = N - 1;
    float4 s0 = part[tid * 4], s1 = part[tid * 4 + 1];
    float4 s2 = part[tid * 4 + 2], s3 = part[tid * 4 + 3];
    float r = rdeg[g2];
    As[tid][0] = (s0.x + s1.x + s2.x + s3.x) * r;
    As[tid][1] = (s0.y + s1.y + s2.y + s3.y) * r;
    As[tid][2] = (s0.z + s1.z + s2.z + s3.z) * r;
    As[tid][3] = (s0.w + s1.w + s2.w + s3.w) * r;
    float4 own = *(const float4*)&xprev[g2 * 4];
    As[tid][4] = own.x; As[tid][5] = own.y; As[tid][6] = own.z; As[tid][7] = own.w;
  }
  __syncthreads();
  int gn2 = nb + nl;
  if (gn2 >= N) return;
  float av[8];
#pragma unroll
  for (int k = 0; k < 8; ++k) av[k] = As[nl][k];
  int o0 = q * 32;
#pragma unroll
  for (int c = 0; c < 4; ++c) {
    ushort8 mt = *(const ushort8*)&mterm[gn2 * 128 + o0 + c * 8];
    ushort8 ov;
#pragma unroll
    for (int oo = 0; oo < 8; ++oo) {
      int o = o0 + c * 8 + oo;
      float s = b2f(mt[oo]);
#pragma unroll
      for (int k = 0; k < 8; ++k) s += av[k] * Wx[k][o];
      ov[oo] = f2bf(fmaxf(s, 0.0f));
    }
    *(ushort8*)&out[gn2 * 128 + o0 + c * 8] = ov;
  }
}

// gather 8 bf16 channels of node gn's neighborhood mean into acc[8]
static __device__ __forceinline__ void gather_mean8(
    const unsigned short* __restrict__ feat, const int* __restrict__ row_ptr,
    const int* __restrict__ col, const float* __restrict__ rdeg,
    int gn, int d, float* acc) {
  int j0 = row_ptr[gn], j1 = row_ptr[gn + 1];
  int j = j0;
  for (; j + 8 <= j1; j += 8) {
    ushort8 v0 = *(const ushort8*)&feat[col[j    ] * 128 + d * 8];
    ushort8 v1 = *(const ushort8*)&feat[col[j + 1] * 128 + d * 8];
    ushort8 v2 = *(const ushort8*)&feat[col[j + 2] * 128 + d * 8];
    ushort8 v3 = *(const ushort8*)&feat[col[j + 3] * 128 + d * 8];
    ushort8 v4 = *(const ushort8*)&feat[col[j + 4] * 128 + d * 8];
    ushort8 v5 = *(const ushort8*)&feat[col[j + 5] * 128 + d * 8];
    ushort8 v6 = *(const ushort8*)&feat[col[j + 6] * 128 + d * 8];
    ushort8 v7 = *(const ushort8*)&feat[col[j + 7] * 128 + d * 8];
#pragma unroll
    for (int r = 0; r < 8; ++r)
      acc[r] += ((b2f(v0[r]) + b2f(v1[r])) + (b2f(v2[r]) + b2f(v3[r]))) +
                ((b2f(v4[r]) + b2f(v5[r])) + (b2f(v6[r]) + b2f(v7[r])));
  }
  for (; j + 2 <= j1; j += 2) {
    ushort8 v0 = *(const ushort8*)&feat[col[j] * 128 + d * 8];
    ushort8 v1 = *(const ushort8*)&feat[col[j + 1] * 128 + d * 8];
#pragma unroll
    for (int r = 0; r < 8; ++r) acc[r] += b2f(v0[r]) + b2f(v1[r]);
  }
  if (j < j1) {
    ushort8 v0 = *(const ushort8*)&feat[col[j] * 128 + d * 8];
#pragma unroll
    for (int r = 0; r < 8; ++r) acc[r] += b2f(v0[r]);
  }
  float rd = rdeg[gn];
#pragma unroll
  for (int r = 0; r < 8; ++r) acc[r] *= rd;
}

#define LDSTRIDE 136   // ushorts; 272B row stride -> conflict-free 16-lane b128 reads

// fused conv: 64 nodes/block. agg -> LDS, then MFMA out = relu([agg|x]@[Wl;Wr]^T+b)
__global__ __launch_bounds__(256, 4) void conv_fused_kernel(
    const unsigned short* __restrict__ h,
    const unsigned short* __restrict__ Wlb, const unsigned short* __restrict__ Wrb,
    const float* __restrict__ bl,
    const int* __restrict__ row_ptr, const int* __restrict__ col,
    const float* __restrict__ rdeg,
    unsigned short* __restrict__ out, int N) {
  __shared__ unsigned short Alds[64 * LDSTRIDE];
  int tid = threadIdx.x;
  int nb = blockIdx.x * 64;
  int d = tid & 15;
  // ---- phase 1: aggregate 64 node rows into LDS (4 passes x 16 nodes) ----
#pragma unroll
  for (int pass = 0; pass < 4; ++pass) {
    int n = pass * 16 + (tid >> 4);
    int gn = nb + n; if (gn > N - 1) gn = N - 1;
    float acc[8] = {};
    gather_mean8(h, row_ptr, col, rdeg, gn, d, acc);
    ushort8 o;
#pragma unroll
    for (int r = 0; r < 8; ++r) o[r] = f2bf(acc[r]);
    *(ushort8*)&Alds[n * LDSTRIDE + d * 8] = o;
  }
  __syncthreads();
  // ---- phase 2: MFMA, 4 waves x 16 nodes ----
  int wave = tid >> 6;
  int lane = tid & 63;
  int wbase = wave * 16;
  int l15 = lane & 15;
  int lk = (lane >> 4) * 8;
  int r0 = nb + wbase + l15; if (r0 > N - 1) r0 = N - 1;

  f32x4 acc[8] = {};
#pragma unroll
  for (int ks = 0; ks < 8; ++ks) {
    short8 a;
    if (ks < 4) a = *(const short8*)&Alds[(wbase + l15) * LDSTRIDE + ks * 32 + lk];
    else        a = *(const short8*)&h[r0 * 128 + (ks - 4) * 32 + lk];
    const unsigned short* Ws = (ks < 4) ? Wlb : Wrb;
    int ko = (ks & 3) * 32 + lk;
#pragma unroll
    for (int ot = 0; ot < 8; ++ot) {
      short8 b = *(const short8*)&Ws[(ot * 16 + l15) * 128 + ko];
      acc[ot] = __builtin_amdgcn_mfma_f32_16x16x32_bf16(a, b, acc[ot], 0, 0, 0);
    }
  }
  int crow = (lane >> 4) * 4;   // C: col = lane&15, row = (lane>>4)*4 + reg
#pragma unroll
  for (int ot = 0; ot < 8; ++ot) {
    int gcol = ot * 16 + l15;
    float bv = bl[gcol];
#pragma unroll
    for (int r = 0; r < 4; ++r) {
      int grow = nb + wbase + crow + r;
      if (grow < N) {
        float v = fmaxf(acc[ot][r] + bv, 0.0f);
        out[grow * 128 + gcol] = f2bf(v);
      }
    }
  }
}

// fused conv + head (dec2): h2 = relu([agg|x]@[Wl;Wr]^T+b) stays in regs;
// x_new = xprev + h2@linW^T + linb; writes out[:,t,:] and xprev.
__global__ __launch_bounds__(256, 4) void conv_head_fused_kernel(
    const unsigned short* __restrict__ h,
    const unsigned short* __restrict__ Wlb, const unsigned short* __restrict__ Wrb,
    const float* __restrict__ bl,
    const int* __restrict__ row_ptr, const int* __restrict__ col,
    const float* __restrict__ rdeg,
    const float* __restrict__ linW, const float* __restrict__ linb,
    float* __restrict__ xprev, float* __restrict__ out, int N, int T, int t) {
  __shared__ unsigned short Alds[64 * LDSTRIDE];
  __shared__ float Wh[4][128];
  int tid = threadIdx.x;
  for (int i = tid; i < 512; i += 256) Wh[i >> 7][i & 127] = linW[i];
  int nb = blockIdx.x * 64;
  int d = tid & 15;
#pragma unroll
  for (int pass = 0; pass < 4; ++pass) {
    int n = pass * 16 + (tid >> 4);
    int gn = nb + n; if (gn > N - 1) gn = N - 1;
    float acc[8] = {};
    gather_mean8(h, row_ptr, col, rdeg, gn, d, acc);
    ushort8 o;
#pragma unroll
    for (int r = 0; r < 8; ++r) o[r] = f2bf(acc[r]);
    *(ushort8*)&Alds[n * LDSTRIDE + d * 8] = o;
  }
  __syncthreads();
  int wave = tid >> 6;
  int lane = tid & 63;
  int wbase = wave * 16;
  int l15 = lane & 15;
  int lk = (lane >> 4) * 8;
  int r0 = nb + wbase + l15; if (r0 > N - 1) r0 = N - 1;

  f32x4 acc[8] = {};
#pragma unroll
  for (int ks = 0; ks < 8; ++ks) {
    short8 a;
    if (ks < 4) a = *(const short8*)&Alds[(wbase + l15) * LDSTRIDE + ks * 32 + lk];
    else        a = *(const short8*)&h[r0 * 128 + (ks - 4) * 32 + lk];
    const unsigned short* Ws = (ks < 4) ? Wlb : Wrb;
    int ko = (ks & 3) * 32 + lk;
#pragma unroll
    for (int ot = 0; ot < 8; ++ot) {
      short8 b = *(const short8*)&Ws[(ot * 16 + l15) * 128 + ko];
      acc[ot] = __builtin_amdgcn_mfma_f32_16x16x32_bf16(a, b, acc[ot], 0, 0, 0);
    }
  }
  // head: part[r][o] = sum_col relu(h2) * linW[o][col]
  float part[4][4] = {};
#pragma unroll
  for (int ot = 0; ot < 8; ++ot) {
    int gcol = ot * 16 + l15;
    float bv = bl[gcol];
    float w0 = Wh[0][gcol], w1 = Wh[1][gcol], w2 = Wh[2][gcol], w3 = Wh[3][gcol];
#pragma unroll
    for (int r = 0; r < 4; ++r) {
      float hv = fmaxf(acc[ot][r] + bv, 0.0f);
      part[r][0] += hv * w0;
      part[r][1] += hv * w1;
      part[r][2] += hv * w2;
      part[r][3] += hv * w3;
    }
  }
#pragma unroll
  for (int m = 1; m < 16; m <<= 1)
#pragma unroll
    for (int r = 0; r < 4; ++r)
#pragma unroll
      for (int o = 0; o < 4; ++o)
        part[r][o] += __shfl_xor(part[r][o], m, 64);

  if (l15 == 0) {
    int crow = (lane >> 4) * 4;
    float4 lb = *(const float4*)linb;
#pragma unroll
    for (int r = 0; r < 4; ++r) {
      int grow = nb + wbase + crow + r;
      if (grow < N) {
        float4 xp = *(const float4*)&xprev[grow * 4];
        float4 xn;
        xn.x = xp.x + part[r][0] + lb.x;
        xn.y = xp.y + part[r][1] + lb.y;
        xn.z = xp.z + part[r][2] + lb.z;
        xn.w = xp.w + part[r][3] + lb.w;
        *(float4*)&out[(grow * T + t) * 4] = xn;
        *(float4*)&xprev[grow * 4] = xn;
      }
    }
  }
}

extern "C" void kernel_launch(void* const* d_in, const int* in_sizes, int n_in,
                              void* d_out, int out_size, void* d_ws, size_t ws_size,
                              hipStream_t stream) {
  const float* F0   = (const float*)d_in[0];
  const float* mesh = (const float*)d_in[1];
  const int*   eidx = (const int*)d_in[2];
  const float* e1Wl = (const float*)d_in[4];
  const float* e1bl = (const float*)d_in[5];
  const float* e1Wr = (const float*)d_in[6];
  const float* e2Wl = (const float*)d_in[7];
  const float* e2bl = (const float*)d_in[8];
  const float* e2Wr = (const float*)d_in[9];
  const float* d1Wl = (const float*)d_in[10];
  const float* d1bl = (const float*)d_in[11];
  const float* d1Wr = (const float*)d_in[12];
  const float* d2Wl = (const float*)d_in[13];
  const float* d2bl = (const float*)d_in[14];
  const float* d2Wr = (const float*)d_in[15];
  const float* linW = (const float*)d_in[16];
  const float* linb = (const float*)d_in[17];

  const int N = in_sizes[0] / 4;
  const int E = in_sizes[2] / 2;
  const int T = out_size / (N * 4);
  const int* src = eidx;
  const int* dst = eidx + E;

  size_t off = 0;
  auto alloc = [&](size_t bytes) -> void* {
    void* p = (char*)d_ws + off;
    off += (bytes + 511) & ~(size_t)511;
    return p;
  };
  int*   cnt     = (int*)alloc((size_t)N * 4);
  int*   row_ptr = (int*)alloc((size_t)(N + 1) * 4);
  int*   rank    = (int*)alloc((size_t)E * 4);
  int*   col     = (int*)alloc((size_t)E * 4);
  float* rdeg    = (float*)alloc((size_t)N * 4);
  float* xprev   = (float*)alloc((size_t)N * 4 * 4);
  float* aggm    = (float*)alloc((size_t)N * 8 * 4);
  int*   bsum    = (int*)alloc(256 * 4);
  int*   boff    = (int*)alloc(256 * 4);
  unsigned short* mterm = (unsigned short*)alloc((size_t)N * 128 * 2);
  unsigned short* h1   = (unsigned short*)alloc((size_t)N * 128 * 2);
  unsigned short* h2   = (unsigned short*)alloc((size_t)N * 128 * 2);
  unsigned short* wb   = (unsigned short*)alloc((size_t)6 * 128 * 128 * 2);
  unsigned short* e2Wlb = wb + 0 * 16384;
  unsigned short* e2Wrb = wb + 1 * 16384;
  unsigned short* d1Wlb = wb + 2 * 16384;
  unsigned short* d1Wrb = wb + 3 * 16384;
  unsigned short* d2Wlb = wb + 4 * 16384;
  unsigned short* d2Wrb = wb + 5 * 16384;

  float* outp = (float*)d_out;

  const int NB = (N + 255) / 256;   // 196 <= 256

  // ---- once per launch: CSR + invariants ----
  hipMemsetAsync(cnt, 0, (size_t)N * 4, stream);
  count_rank_kernel<<<(E + 255) / 256, 256, 0, stream>>>(dst, cnt, rank, E);
  blocksum_kernel<<<NB, 256, 0, stream>>>(cnt, bsum, N);
  scan_sums_kernel<<<1, 256, 0, stream>>>(bsum, boff, NB);
  expand_kernel<<<NB, 256, 0, stream>>>(cnt, boff, row_ptr, rdeg, N);
  fill_csr2_kernel<<<(E + 255) / 256, 256, 0, stream>>>(src, dst, rank, row_ptr, col, E);
  f2bf6_kernel<<<(6 * 16384 + 255) / 256, 256, 0, stream>>>(
      e2Wl, e2Wr, d1Wl, d1Wr, d2Wl, d2Wr, wb);
  aggmesh_kernel<<<(N * 2 + 255) / 256, 256, 0, stream>>>(mesh, aggm, row_ptr, col, rdeg, N);
  mesh_term_kernel<<<(N * 128 + 255) / 256, 256, 0, stream>>>(aggm, mesh, e1Wl, e1Wr, e1bl,
                                                              mterm, N);
  hipMemcpyAsync(xprev, F0, (size_t)N * 4 * 4, hipMemcpyDeviceToDevice, stream);

  const int gConv = (N + 63) / 64;
  const int gEnc1 = (N + 63) / 64;

  for (int t = 0; t < T; ++t) {
    enc1_kernel<<<gEnc1, 256, 0, stream>>>(xprev, row_ptr, col, rdeg,
                                           e1Wl, e1Wr, mterm, h1, N);
    conv_fused_kernel<<<gConv, 256, 0, stream>>>(h1, e2Wlb, e2Wrb, e2bl,
                                                 row_ptr, col, rdeg, h2, N);
    conv_fused_kernel<<<gConv, 256, 0, stream>>>(h2, d1Wlb, d1Wrb, d1bl,
                                                 row_ptr, col, rdeg, h1, N);
    conv_head_fused_kernel<<<gConv, 256, 0, stream>>>(h1, d2Wlb, d2Wrb, d2bl,
                                                      row_ptr, col, rdeg,
                                                      linW, linb, xprev, outp, N, T, t);
  }
}